// Round 4
// baseline (92.708 us; speedup 1.0000x reference)
//
#include <hip/hip_runtime.h>

#define BB 8
#define TT 512
#define DD 64
#define IT 4            // i-rows per block, one per wave
#define JTILE 64        // j-rows per LDS tile
#define NTILE 4         // tiles per block (block owns a 256-j half)
#define GR 17           // float4-granules per padded LDS row (16 data + 1 pad)
#define S_SCALE 1.2011224087864498f   // sqrt(log2(e)); exp(-u^2) = exp2(-(S*u)^2)

__device__ __forceinline__ float fast_exp2(float v) {
#if __has_builtin(__builtin_amdgcn_exp2f)
    return __builtin_amdgcn_exp2f(v);
#else
    return exp2f(v);
#endif
}
__device__ __forceinline__ float fast_rcp(float v) {
#if __has_builtin(__builtin_amdgcn_rcpf)
    return __builtin_amdgcn_rcpf(v);
#else
    return 1.0f / v;
#endif
}

// Sum across the 4 lanes of a quad via DPP quad_perm butterfly (VALU-only,
// no LDS pipe). After both stages every lane holds the quad total.
__device__ __forceinline__ float quad_sum(float v) {
    int s1 = __builtin_amdgcn_update_dpp(0, __float_as_int(v),
                                         177 /*quad_perm [1,0,3,2]*/, 0xf, 0xf, true);
    float a = v + __int_as_float(s1);
    int s2 = __builtin_amdgcn_update_dpp(0, __float_as_int(a),
                                         78 /*quad_perm [2,3,0,1]*/, 0xf, 0xf, true);
    return a + __int_as_float(s2);
}

// Block = 4 waves; wave w owns row i = itile*4 + w; block owns a 256-j half.
// Lane l = jg*4 + dg: within each 16-output group, lane handles output jg with
// d-slice [dg*16, dg*16+16). xi/vi are 16 floats/lane (32 VGPRs total) -> low
// register state, high occupancy. Quad reduction via DPP. xj staged scaled in
// padded LDS (aligned b128, conflict-free spread), single-buffered.
__global__ __launch_bounds__(256, 6) void rbf_fused4(
    const float* __restrict__ x,     // (B,T,D)
    const float* __restrict__ W,     // (D,D)
    const float* __restrict__ bias,  // (D,)
    float* __restrict__ out)         // (B,T,T)
{
    const int blk = blockIdx.x;      // ((b*128 + itile)*2 + jh)
    const int jh  = blk & 1;
    const int it8 = (blk >> 1) & 127;
    const int b   = blk >> 8;
    const int t   = threadIdx.x;
    const int w   = t >> 6;
    const int l   = t & 63;
    const int dg  = l & 3;           // d-slice within quad
    const int jg  = l >> 2;          // output index within 16-group

    __shared__ float xi_s[IT][DD];                 // scaled by S
    __shared__ float vi_s[IT][DD];
    __shared__ float4 xj_s[JTILE * GR];            // scaled by S, granule-padded

    // ---- phase 1: v = x@W^T + b for the 4 i-rows; stage xi*S ----
    const float* xrow = x + (size_t)(b * TT + it8 * IT + w) * DD;
    {
        const float* wr = W + (size_t)l * DD;
        float acc = bias[l];
        #pragma unroll
        for (int d = 0; d < DD; d += 4) {
            float4 xv = *(const float4*)(xrow + d);
            float4 wv = *(const float4*)(wr + d);
            acc = fmaf(xv.x, wv.x, acc); acc = fmaf(xv.y, wv.y, acc);
            acc = fmaf(xv.z, wv.z, acc); acc = fmaf(xv.w, wv.w, acc);
        }
        vi_s[w][l] = acc;
        xi_s[w][l] = xrow[l] * S_SCALE;
    }
    __syncthreads();

    // per-lane d-slice of xi (scaled) and vi: 4 float4 each = 32 VGPRs
    float4 xi_r[4], vi_r[4];
    #pragma unroll
    for (int c = 0; c < 4; ++c) {
        xi_r[c] = *(const float4*)(&xi_s[w][dg * 16 + c * 4]);
        vi_r[c] = *(const float4*)(&vi_s[w][dg * 16 + c * 4]);
    }

    const float* xb = x + ((size_t)b * TT + (size_t)jh * 256) * DD;
    float* orow = out + (size_t)(b * TT + it8 * IT + w) * TT + jh * 256;

    // staging map: thread covers granules g = u*256 + t: row = g>>4, col = g&15
    const int sr = t >> 4;
    const int sc = t & 15;

    // ---- stage tile 0 ----
    #pragma unroll
    for (int u = 0; u < 4; ++u) {
        float4 v = *(const float4*)(xb + (size_t)(u * 16 + sr) * DD + sc * 4);
        v.x *= S_SCALE; v.y *= S_SCALE; v.z *= S_SCALE; v.w *= S_SCALE;
        xj_s[(u * 16 + sr) * GR + sc] = v;
    }
    __syncthreads();

    for (int jt = 0; jt < NTILE; ++jt) {
        // ---- compute 4 groups of 16 outputs ----
        #pragma unroll
        for (int g = 0; g < 4; ++g) {
            const float4* base = &xj_s[(g * 16 + jg) * GR + dg * 4];
            float n0 = 0.f, n1 = 0.f, e0s = 0.f, e1s = 0.f;
            #pragma unroll
            for (int c = 0; c < 4; ++c) {
                float4 xj = base[c];
                float4 xi = xi_r[c];
                float4 vi = vi_r[c];
                float u0 = xi.x - xj.x;
                float u1 = xi.y - xj.y;
                float u2 = xi.z - xj.z;
                float u3 = xi.w - xj.w;
                float e0 = fast_exp2(-(u0 * u0));
                float e1 = fast_exp2(-(u1 * u1));
                float e2 = fast_exp2(-(u2 * u2));
                float e3 = fast_exp2(-(u3 * u3));
                n0 = fmaf(e0, vi.x, n0);
                n1 = fmaf(e1, vi.y, n1);
                n0 = fmaf(e2, vi.z, n0);
                n1 = fmaf(e3, vi.w, n1);
                e0s += e0 + e2;
                e1s += e1 + e3;
            }
            float num = quad_sum(n0 + n1);
            float den = quad_sum(e0s + e1s);
            if (dg == 0)
                orow[jt * JTILE + g * 16 + jg] = num * fast_rcp(den);
        }
        // ---- stage next tile (single buffer: barrier, write, barrier) ----
        if (jt + 1 < NTILE) {
            __syncthreads();
            #pragma unroll
            for (int u = 0; u < 4; ++u) {
                float4 v = *(const float4*)(
                    xb + (size_t)((jt + 1) * JTILE + u * 16 + sr) * DD + sc * 4);
                v.x *= S_SCALE; v.y *= S_SCALE; v.z *= S_SCALE; v.w *= S_SCALE;
                xj_s[(u * 16 + sr) * GR + sc] = v;
            }
            __syncthreads();
        }
    }
}

extern "C" void kernel_launch(void* const* d_in, const int* in_sizes, int n_in,
                              void* d_out, int out_size, void* d_ws, size_t ws_size,
                              hipStream_t stream) {
    const float* x    = (const float*)d_in[0];
    const float* W    = (const float*)d_in[1];
    const float* bias = (const float*)d_in[2];
    float* out        = (float*)d_out;

    rbf_fused4<<<BB * (TT / IT) * 2, 256, 0, stream>>>(x, W, bias, out);
}